// Round 7
// baseline (661.687 us; speedup 1.0000x reference)
//
#include <hip/hip_runtime.h>
#include <math.h>

#define NEG 0.01f

typedef _Float16 f16;
typedef f16 h2 __attribute__((ext_vector_type(2)));
typedef f16 h4 __attribute__((ext_vector_type(4)));
typedef float f32x4 __attribute__((ext_vector_type(4)));

__device__ __forceinline__ float lrelu(float x) { return x > 0.f ? x : NEG * x; }

// sum across each 16-lane row via DPP; result in all 16 lanes of the row
__device__ __forceinline__ float q16_allsum(float v) {
    int x;
    x = __builtin_amdgcn_update_dpp(0, __float_as_int(v), 0xB1, 0xF, 0xF, true);  v += __int_as_float(x); // quad_perm xor1
    x = __builtin_amdgcn_update_dpp(0, __float_as_int(v), 0x4E, 0xF, 0xF, true);  v += __int_as_float(x); // quad_perm xor2
    x = __builtin_amdgcn_update_dpp(0, __float_as_int(v), 0x124, 0xF, 0xF, true); v += __int_as_float(x); // row_ror:4
    x = __builtin_amdgcn_update_dpp(0, __float_as_int(v), 0x128, 0xF, 0xF, true); v += __int_as_float(x); // row_ror:8
    return v;
}

__device__ __forceinline__ float x16_32_sum(float v) {
    v += __int_as_float(__builtin_amdgcn_ds_swizzle(__float_as_int(v), 0x401F)); // xor 16
    v += __shfl_xor(v, 32, 64);
    return v;
}

// ---------------- k_pre: zero deg + zero rec pads + pack MFMA B-frags ----
// wpack2[i], i = ((L*5+s)*4+nb)*64+lane : 4 f16 of W1[L] column f=nb*16+(lane&15),
// rows k = s*16+(lane>>4)*4 .. +3 (0 beyond row 70).  3 layers x 5 ksteps x 4 nb.
__global__ void k_pre(int* __restrict__ deg, int N,
                      const float* __restrict__ lin1, uint2* __restrict__ wpack2,
                      uint4* __restrict__ rec, int E) {
    int i = blockIdx.x * blockDim.x + threadIdx.x;
    if (i < N) deg[i] = 0;
    if (i < 3840) {
        int lane = i & 63, rest = i >> 6;
        int nb = rest & 3, rest2 = rest >> 2;
        int s = rest2 % 5, L = rest2 / 5;
        int f  = nb * 16 + (lane & 15);
        int kb = s * 16 + ((lane >> 4) << 2);
        const float* W = lin1 + (size_t)L * 71 * 64;
        float v0 = (kb + 0 < 71) ? W[(kb + 0) * 64 + f] : 0.f;
        float v1 = (kb + 1 < 71) ? W[(kb + 1) * 64 + f] : 0.f;
        float v2 = (kb + 2 < 71) ? W[(kb + 2) * 64 + f] : 0.f;
        float v3 = (kb + 3 < 71) ? W[(kb + 3) * 64 + f] : 0.f;
        h2 p01 = { (f16)v0, (f16)v1 };
        h2 p23 = { (f16)v2, (f16)v3 };
        uint2 u;
        u.x = __builtin_bit_cast(unsigned int, p01);
        u.y = __builtin_bit_cast(unsigned int, p23);
        wpack2[i] = u;
    }
    if (i >= 3840 && i < 3904) rec[E + i - 3840] = make_uint4(0, 0, 0, 0);
}

// fused: blocks [0,nbC): degree count (4 edges/thread); blocks [nbC,..):
// layer-0 prep (no LDS): hcat[:,0:64]=emb[x], h16=f16(emb[x]), r=emb[x].ar0
__global__ __launch_bounds__(256) void k_count_h0(
    const int* __restrict__ dst, int* __restrict__ deg, int* __restrict__ rank,
    int E, int nbC,
    const int* __restrict__ x, const float* __restrict__ emb,
    const float* __restrict__ ar0,
    f16* __restrict__ h16, float* __restrict__ r_out,
    float* __restrict__ hcat, int N)
{
    int tid = threadIdx.x;
    if ((int)blockIdx.x < nbC) {
        int e = (blockIdx.x * 256 + tid) * 4;
        if (e + 3 < E) {
            int4 d = *(const int4*)(dst + e);
            int r0 = atomicAdd(&deg[d.x], 1);
            int r1 = atomicAdd(&deg[d.y], 1);
            int r2 = atomicAdd(&deg[d.z], 1);
            int r3 = atomicAdd(&deg[d.w], 1);
            *(int4*)(rank + e) = make_int4(r0, r1, r2, r3);
        } else {
            for (int k = 0; k < 4; k++)
                if (e + k < E) rank[e + k] = atomicAdd(&deg[dst[e + k]], 1);
        }
        return;
    }
    int idx = ((int)blockIdx.x - nbC) * 256 + tid;
    int node = idx >> 4, sub = idx & 15;
    if (node >= N) return;
    int j4 = sub * 4;
    float4 em = *(const float4*)(emb + (size_t)x[node] * 64 + j4);
    *(float4*)(hcat + (size_t)node * 256 + j4) = em;
    uint2 hw;
    hw.x = __builtin_bit_cast(unsigned int, __builtin_amdgcn_cvt_pkrtz(em.x, em.y));
    hw.y = __builtin_bit_cast(unsigned int, __builtin_amdgcn_cvt_pkrtz(em.z, em.w));
    *(uint2*)(h16 + (size_t)node * 64 + j4) = hw;
    float part = em.x * ar0[j4] + em.y * ar0[j4 + 1]
               + em.z * ar0[j4 + 2] + em.w * ar0[j4 + 3];
    part = q16_allsum(part);
    if (sub == 0) r_out[node] = part;
}

__global__ __launch_bounds__(256) void k_scan_part(const int* __restrict__ deg,
                                                   int* __restrict__ bsum, int n) {
    __shared__ int sh[256];
    int b = blockIdx.x, t = threadIdx.x;
    int i0 = b * 1024 + t * 4;
    int s = 0;
    if (i0 + 3 < n) { int4 v = *(const int4*)(deg + i0); s = v.x + v.y + v.z + v.w; }
    else { for (int k = 0; k < 4; k++) if (i0 + k < n) s += deg[i0 + k]; }
    sh[t] = s; __syncthreads();
    for (int d = 128; d > 0; d >>= 1) { if (t < d) sh[t] += sh[t + d]; __syncthreads(); }
    if (t == 0) bsum[b] = sh[0];
}

// every block redundantly scans bsum (nb<=256), then emits its 1024 offsets
__global__ __launch_bounds__(256) void k_scan_out(const int* __restrict__ deg,
                                                  const int* __restrict__ bsum,
                                                  int* __restrict__ off, int nb, int n) {
    __shared__ int sb[256];
    __shared__ int sh[256];
    int b = blockIdx.x, t = threadIdx.x;
    int v = (t < nb) ? bsum[t] : 0;
    sb[t] = v; __syncthreads();
    for (int d = 1; d < 256; d <<= 1) {
        int u = (t >= d) ? sb[t - d] : 0;
        __syncthreads(); sb[t] += u; __syncthreads();
    }
    int base = (b == 0) ? 0 : sb[b - 1];
    if (b == 0 && t == 0) off[n] = sb[255];
    int i0 = b * 1024 + t * 4;
    int4 v4 = make_int4(0, 0, 0, 0);
    if (i0 + 3 < n) v4 = *(const int4*)(deg + i0);
    else {
        v4.x = (i0     < n) ? deg[i0]     : 0;
        v4.y = (i0 + 1 < n) ? deg[i0 + 1] : 0;
        v4.z = (i0 + 2 < n) ? deg[i0 + 2] : 0;
        v4.w = (i0 + 3 < n) ? deg[i0 + 3] : 0;
    }
    int s = v4.x + v4.y + v4.z + v4.w;
    sh[t] = s; __syncthreads();
    for (int d = 1; d < 256; d <<= 1) {
        int u = (t >= d) ? sh[t - d] : 0;
        __syncthreads(); sh[t] += u; __syncthreads();
    }
    int ex = base + sh[t] - s;
    if (i0     < n) off[i0]     = ex;
    if (i0 + 1 < n) off[i0 + 1] = ex + v4.x;
    if (i0 + 2 < n) off[i0 + 2] = ex + v4.x + v4.y;
    if (i0 + 3 < n) off[i0 + 3] = ex + v4.x + v4.y + v4.z;
}

// build 16B fp16 edge records, 2 edges/thread; slot = off[dst] + rank (no atomics)
__global__ void k_fill(const int* __restrict__ src, const int* __restrict__ dst,
                       const float* __restrict__ eattr, const int* __restrict__ off,
                       const int* __restrict__ rank, uint4* __restrict__ rec, int E) {
    int e = (blockIdx.x * 256 + threadIdx.x) * 2;
    if (e >= E) return;
    bool two = (e + 1 < E);
#pragma unroll
    for (int k = 0; k < 2; k++) {
        if (k == 1 && !two) break;
        int ee = e + k;
        int slot = off[dst[ee]] + rank[ee];
        const float* ap = eattr + (size_t)ee * 7;
        float a0 = ap[0], a1 = ap[1], a2 = ap[2], a3 = ap[3], a4 = ap[4], a5 = ap[5], a6 = ap[6];
        uint4 rv;
        h2 p01 = { (f16)a0, (f16)a1 };
        h2 p23 = { (f16)a2, (f16)a3 };
        h2 p45 = { (f16)a4, (f16)a5 };
        rv.x = __builtin_bit_cast(unsigned int, p01);
        rv.y = __builtin_bit_cast(unsigned int, p23);
        rv.z = __builtin_bit_cast(unsigned int, p45);
        unsigned int a6b = (unsigned int)__builtin_bit_cast(unsigned short, (f16)a6);
        rv.w = a6b | ((unsigned int)src[ee] << 16);   // requires N < 65536
        rec[slot] = rv;
    }
}

// gemm2(layer l) + next-layer prep, 64-row tiles:
//   out1 = relu(agg@W2 + b) -> hc (in-place, stride 256)
//   h16  = f16(out1),  r = out1 . arn   (inputs for next conv layer)
__global__ __launch_bounds__(256) void k_gemm2h(
    float* __restrict__ hc,
    const float* __restrict__ W2, const float* __restrict__ bias,
    const float* __restrict__ arn,
    f16* __restrict__ h16, float* __restrict__ r_out, int N)
{
    __shared__ __align__(16) float sA[64][68];
    __shared__ __align__(16) float sB[64 * 64];
    __shared__ float sar[64];
    int tid = threadIdx.x, row0 = blockIdx.x * 64;

    {
        const float4* b4 = (const float4*)W2;
        float4* s4 = (float4*)sB;
        for (int i = tid; i < 1024; i += 256) s4[i] = b4[i];
    }
    if (tid < 64) sar[tid] = arn[tid];

#pragma unroll
    for (int pass = 0; pass < 4; ++pass) {
        int nl = pass * 16 + (tid & 15);
        int k4 = (tid >> 4) * 4;
        int n = row0 + nl; if (n >= N) n = N - 1;
        float4 v = *(const float4*)(hc + (size_t)n * 256 + k4);
        sA[k4 + 0][nl] = v.x; sA[k4 + 1][nl] = v.y;
        sA[k4 + 2][nl] = v.z; sA[k4 + 3][nl] = v.w;
    }
    __syncthreads();

    int tr = tid >> 4, tc = tid & 15;
    int r0 = tr * 4, c0 = tc * 4;
    float acc[4][4];
#pragma unroll
    for (int i = 0; i < 4; i++)
#pragma unroll
        for (int j = 0; j < 4; j++) acc[i][j] = 0.f;

#pragma unroll 4
    for (int k = 0; k < 64; ++k) {
        float4 b4 = *(const float4*)(sB + k * 64 + c0);
        float4 a0 = *(const float4*)&sA[k][r0];
#pragma unroll
        for (int j = 0; j < 4; j++) {
            float bj = (&b4.x)[j];
            acc[0][j] += a0.x * bj; acc[1][j] += a0.y * bj;
            acc[2][j] += a0.z * bj; acc[3][j] += a0.w * bj;
        }
    }

    float4 bv = *(const float4*)(bias + c0);
#pragma unroll
    for (int i = 0; i < 4; i++) {
        acc[i][0] = fmaxf(acc[i][0] + bv.x, 0.f);
        acc[i][1] = fmaxf(acc[i][1] + bv.y, 0.f);
        acc[i][2] = fmaxf(acc[i][2] + bv.z, 0.f);
        acc[i][3] = fmaxf(acc[i][3] + bv.w, 0.f);
        int n = row0 + r0 + i;
        if (n < N) {
            *(float4*)(hc + (size_t)n * 256 + c0) =
                make_float4(acc[i][0], acc[i][1], acc[i][2], acc[i][3]);
            uint2 hw;
            hw.x = __builtin_bit_cast(unsigned int, __builtin_amdgcn_cvt_pkrtz(acc[i][0], acc[i][1]));
            hw.y = __builtin_bit_cast(unsigned int, __builtin_amdgcn_cvt_pkrtz(acc[i][2], acc[i][3]));
            *(uint2*)(h16 + (size_t)n * 64 + c0) = hw;
        }
    }
    // r = out1 . arn : per-thread partial over its 4 cols, DPP-reduce 16 tc lanes
#pragma unroll
    for (int i = 0; i < 4; i++) {
        float part = acc[i][0] * sar[c0] + acc[i][1] * sar[c0 + 1]
                   + acc[i][2] * sar[c0 + 2] + acc[i][3] * sar[c0 + 3];
        part = q16_allsum(part);
        if (tc == 0) {
            int n = row0 + r0 + i;
            if (n < N) r_out[n] = part;
        }
    }
}

// ---------------- gate conv: wave/node, 16 edges/wave-iter via MFMA ----
// xj[16 edges][64 feats] = [h16[src] | attr](K=80 padded) @ W1 via
// 20x v_mfma_f32_16x16x16f16 (5 K-steps x 4 N-blocks).
// A: row=lane&15 (edge), k=s*16+(lane>>4)*4+j.  B: packed in wpack2.
// D: col=lane&15 (feat within block), row=(lane>>4)*4+reg (edge).
__global__ __launch_bounds__(256) void k_conv(
    const int* __restrict__ off, const uint4* __restrict__ rec,
    const f16* __restrict__ h16, const float* __restrict__ r,
    const uint2* __restrict__ wp2, const float* __restrict__ al,
    float* __restrict__ aggdst, int N)
{
    int lane = threadIdx.x & 63;
    int wid  = threadIdx.x >> 6;
    int node = blockIdx.x * 4 + wid;
    if (node >= N) return;                 // wave-uniform exit, no barriers
    int l16 = lane & 15, grp = lane >> 4;

    h4 B[5][4];
#pragma unroll
    for (int s = 0; s < 5; s++)
#pragma unroll
        for (int nb = 0; nb < 4; nb++)
            B[s][nb] = __builtin_bit_cast(h4, wp2[(s * 4 + nb) * 64 + lane]);

    float alv0 = al[l16], alv1 = al[16 + l16], alv2 = al[32 + l16], alv3 = al[48 + l16];
    float ri = r[node];
    int e0 = off[node], e1 = off[node + 1];

    float facc0 = 0.f, facc1 = 0.f, facc2 = 0.f, facc3 = 0.f, pden = 0.f;

    if (e0 < e1) {
        // prologue: iter-0 rec + h16 row (rec padded+zeroed past E)
        uint4 rv = rec[e0 + l16];
        const uint2* hp = (const uint2*)(h16 + (size_t)(rv.w >> 16) * 64) + grp;
        uint2 a0 = hp[0], a1 = hp[4], a2 = hp[8], a3 = hp[12];
        for (int e = e0; e < e1; e += 16) {
            // prefetch next iter
            uint4 rvn = rec[e + 16 + l16];
            const uint2* hpn = (const uint2*)(h16 + (size_t)(rvn.w >> 16) * 64) + grp;
            uint2 b0 = hpn[0], b1 = hpn[4], b2 = hpn[8], b3 = hpn[12];

            // attr K-step frag: k=64..79; grp0 -> a0..a3, grp1 -> a4,a5,a6,0
            uint2 at = make_uint2(0u, 0u);
            if (grp == 0)      at = make_uint2(rv.x, rv.y);
            else if (grp == 1) at = make_uint2(rv.z, rv.w & 0xFFFFu);

            h4 A0 = __builtin_bit_cast(h4, a0), A1 = __builtin_bit_cast(h4, a1);
            h4 A2 = __builtin_bit_cast(h4, a2), A3 = __builtin_bit_cast(h4, a3);
            h4 A4 = __builtin_bit_cast(h4, at);
            f32x4 acc0 = {0.f,0.f,0.f,0.f}, acc1 = {0.f,0.f,0.f,0.f};
            f32x4 acc2 = {0.f,0.f,0.f,0.f}, acc3 = {0.f,0.f,0.f,0.f};
#define MF(ACC, NB) \
            ACC = __builtin_amdgcn_mfma_f32_16x16x16f16(A0, B[0][NB], ACC, 0, 0, 0); \
            ACC = __builtin_amdgcn_mfma_f32_16x16x16f16(A1, B[1][NB], ACC, 0, 0, 0); \
            ACC = __builtin_amdgcn_mfma_f32_16x16x16f16(A2, B[2][NB], ACC, 0, 0, 0); \
            ACC = __builtin_amdgcn_mfma_f32_16x16x16f16(A3, B[3][NB], ACC, 0, 0, 0); \
            ACC = __builtin_amdgcn_mfma_f32_16x16x16f16(A4, B[4][NB], ACC, 0, 0, 0);
            MF(acc0, 0) MF(acc1, 1) MF(acc2, 2) MF(acc3, 3)
#undef MF
            // lrelu in f32; lane holds 4 edges (rows grp*4+reg) x 4 feats
            float x0[4], x1[4], x2[4], x3[4];
#pragma unroll
            for (int g2 = 0; g2 < 4; g2++) {
                x0[g2] = fmaxf(acc0[g2], NEG * acc0[g2]);
                x1[g2] = fmaxf(acc1[g2], NEG * acc1[g2]);
                x2[g2] = fmaxf(acc2[g2], NEG * acc2[g2]);
                x3[g2] = fmaxf(acc3[g2], NEG * acc3[g2]);
            }
#pragma unroll
            for (int reg = 0; reg < 4; reg++) {
                float pp = x0[reg] * alv0 + x1[reg] * alv1
                         + x2[reg] * alv2 + x3[reg] * alv3;
                pp = q16_allsum(pp);            // sum over the 16 feat-cols
                float alpha = lrelu(pp + ri);
                int eg = e + grp * 4 + reg;
                float w = (eg < e1) ? __expf(alpha) : 0.f;  // |alpha| bounded
                facc0 += w * x0[reg]; facc1 += w * x1[reg];
                facc2 += w * x2[reg]; facc3 += w * x3[reg];
                pden += w;
            }
            rv = rvn; a0 = b0; a1 = b1; a2 = b2; a3 = b3;
        }
    }
    // reduce across the 4 row-groups (lanes l, l^16, l^32, l^48 share feat)
    facc0 = x16_32_sum(facc0); facc1 = x16_32_sum(facc1);
    facc2 = x16_32_sum(facc2); facc3 = x16_32_sum(facc3);
    pden  = x16_32_sum(pden);
    float inv = 1.f / (pden + 1e-16f);
    if (grp == 0) {
        float* o = aggdst + (size_t)node * 256;
        o[l16]      = facc0 * inv;
        o[16 + l16] = facc1 * inv;
        o[32 + l16] = facc2 * inv;
        o[48 + l16] = facc3 * inv;
    }
}

// ---------------- fused final gemm2 (layer 2) + head ----------------
// h3 = relu(agg2@W2 + b) stays in LDS (never written to hcat);
// head threads remapped pairwise (row=tid>>1, half=tid&1) -> shfl_xor combine.
__global__ __launch_bounds__(256) void k_gemm2head(
    const float* __restrict__ hcat,
    const float* __restrict__ W2, const float* __restrict__ bias,
    const float* __restrict__ f1w, const float* __restrict__ f1b,
    const float* __restrict__ f2w, const float* __restrict__ f2b,
    float* __restrict__ out, int N)
{
    __shared__ __align__(16) float sA[64][130];   // gemm A staging, then sO[128][65]
    __shared__ __align__(16) float sBW[5120];     // W2 (4096), then f1w (5120)
    int tid = threadIdx.x, row0 = blockIdx.x * 128;

    {
        const float4* b4 = (const float4*)W2;
        float4* s4 = (float4*)sBW;
        for (int i = tid; i < 1024; i += 256) s4[i] = b4[i];
    }
#pragma unroll
    for (int pass = 0; pass < 8; ++pass) {
        int nl = pass * 16 + (tid & 15);
        int k4 = (tid >> 4) * 4;
        int n = row0 + nl; if (n >= N) n = N - 1;
        float4 v = *(const float4*)(hcat + (size_t)n * 256 + 192 + k4);
        sA[k4 + 0][nl] = v.x; sA[k4 + 1][nl] = v.y;
        sA[k4 + 2][nl] = v.z; sA[k4 + 3][nl] = v.w;
    }
    __syncthreads();

    int tr = tid >> 4, tc = tid & 15;
    int r0 = tr * 8, c0 = tc * 4;
    float acc[8][4];
#pragma unroll
    for (int i = 0; i < 8; i++)
#pragma unroll
        for (int j = 0; j < 4; j++) acc[i][j] = 0.f;

#pragma unroll 4
    for (int k = 0; k < 64; ++k) {
        float4 b4 = *(const float4*)(sBW + k * 64 + c0);
        float4 a0 = *(const float4*)&sA[k][r0];
        float4 a1 = *(const float4*)&sA[k][r0 + 4];
#pragma unroll
        for (int j = 0; j < 4; j++) {
            float bj = (&b4.x)[j];
            acc[0][j] += a0.x * bj; acc[1][j] += a0.y * bj;
            acc[2][j] += a0.z * bj; acc[3][j] += a0.w * bj;
            acc[4][j] += a1.x * bj; acc[5][j] += a1.y * bj;
            acc[6][j] += a1.z * bj; acc[7][j] += a1.w * bj;
        }
    }

    // issue f1w loads early (write to LDS only after the sync)
    float4 fw[5];
    {
        const float4* w4 = (const float4*)f1w;
#pragma unroll
        for (int i2 = 0; i2 < 5; i2++) fw[i2] = w4[tid + i2 * 256];
    }
    __syncthreads();   // everyone done reading sA/sBW

    float* sO = &sA[0][0];          // [128][65] = 8320 = 64*130 floats exactly
    float4 bv = *(const float4*)(bias + c0);
#pragma unroll
    for (int i = 0; i < 8; i++) {
        acc[i][0] = fmaxf(acc[i][0] + bv.x, 0.f);
        acc[i][1] = fmaxf(acc[i][1] + bv.y, 0.f);
        acc[i][2] = fmaxf(acc[i][2] + bv.z, 0.f);
        acc[i][3] = fmaxf(acc[i][3] + bv.w, 0.f);
        int rr = r0 + i;
        sO[rr * 65 + c0 + 0] = acc[i][0];
        sO[rr * 65 + c0 + 1] = acc[i][1];
        sO[rr * 65 + c0 + 2] = acc[i][2];
        sO[rr * 65 + c0 + 3] = acc[i][3];
    }
    {
        float4* sw4 = (float4*)sBW;
#pragma unroll
        for (int i2 = 0; i2 < 5; i2++) sw4[tid + i2 * 256] = fw[i2];
    }
    __syncthreads();

    // head: row = tid>>1, half = tid&1 (pair lanes adjacent -> shfl combine)
    int rloc = tid >> 1;
    int half = tid & 1;
    int n = row0 + rloc;
    int nn = (n < N) ? n : N - 1;
    float z[20];
#pragma unroll
    for (int j = 0; j < 20; j++) z[j] = 0.f;
    const float4* hr = (const float4*)(hcat + (size_t)nn * 256);
    if (half == 0) {
        for (int k4 = 0; k4 < 32; k4++) {
            float4 h = hr[k4];
            const float* wr = sBW + k4 * 80;
#pragma unroll
            for (int j = 0; j < 20; j++)
                z[j] += h.x * wr[j] + h.y * wr[20 + j] + h.z * wr[40 + j] + h.w * wr[60 + j];
        }
    } else {
        for (int k4 = 32; k4 < 48; k4++) {
            float4 h = hr[k4];
            const float* wr = sBW + k4 * 80;
#pragma unroll
            for (int j = 0; j < 20; j++)
                z[j] += h.x * wr[j] + h.y * wr[20 + j] + h.z * wr[40 + j] + h.w * wr[60 + j];
        }
        for (int k = 0; k < 64; k += 2) {
            float hx = sO[rloc * 65 + k], hy = sO[rloc * 65 + k + 1];
            const float* wr = sBW + (192 + k) * 20;
#pragma unroll
            for (int j = 0; j < 20; j++)
                z[j] += hx * wr[j] + hy * wr[20 + j];
        }
    }
    // combine halves: lanes (2i, 2i+1) hold the two partials of row i
#pragma unroll
    for (int j = 0; j < 20; j++) z[j] += __shfl_xor(z[j], 1, 64);
    if (half == 0 && n < N) {
        float o = f2b[0];
#pragma unroll
        for (int j = 0; j < 20; j++) {
            float zj = z[j] + f1b[j];
            o += fmaxf(zj, 0.f) * f2w[j];
        }
        out[n] = 1.f / (1.f + __expf(-o));
    }
}

extern "C" void kernel_launch(void* const* d_in, const int* in_sizes, int n_in,
                              void* d_out, int out_size, void* d_ws, size_t ws_size,
                              hipStream_t stream) {
    const int*   x     = (const int*)d_in[0];
    const int*   eidx  = (const int*)d_in[1];
    const float* eattr = (const float*)d_in[2];
    const float* emb   = (const float*)d_in[3];
    const float* lin1  = (const float*)d_in[4];   // [3,71,64]
    const float* attl  = (const float*)d_in[5];   // [3,64]
    const float* attr_ = (const float*)d_in[6];   // [3,64]
    const float* lin2  = (const float*)d_in[7];   // [3,64,64]
    const float* gbias = (const float*)d_in[8];   // [3,64]
    const float* f1w   = (const float*)d_in[9];   // [256,20]
    const float* f1b   = (const float*)d_in[10];
    const float* f2w   = (const float*)d_in[11];
    const float* f2b   = (const float*)d_in[12];
    float* out = (float*)d_out;

    int N = in_sizes[0];
    int E = in_sizes[1] / 2;
    const int* src = eidx;
    const int* dst = eidx + E;

    // workspace carve (256B aligned)
    char* p = (char*)d_ws;
    auto alloc = [&](size_t bytes) { void* q = (void*)p; p += (bytes + 255) & ~(size_t)255; return q; };
    float* hcat = (float*)alloc((size_t)N * 256 * 4);
    f16*   h16  = (f16*)alloc((size_t)N * 64 * 2);
    float* r    = (float*)alloc((size_t)N * 4);
    int*   off  = (int*)alloc((size_t)(N + 1) * 4);
    int*   deg  = (int*)alloc((size_t)N * 4);
    int*   rank = (int*)alloc((size_t)E * 4);
    int*   bsum = (int*)alloc(256 * 4);
    uint4* rec  = (uint4*)alloc((size_t)(E + 64) * 16);   // +64 zeroed pad slots
    uint2* wpack2 = (uint2*)alloc((size_t)3840 * 8);      // MFMA B-frags, 3 layers

    int nbs   = (N + 1023) / 1024;             // 49 scan blocks (<=256)
    int nbC   = ((E + 3) / 4 + 255) / 256;     // count blocks, 4 edges/thread
    int nbH0  = (N * 16 + 255) / 256;          // layer-0 prep blocks
    int nbF   = ((E + 1) / 2 + 255) / 256;     // fill blocks, 2 edges/thread
    int nbg64 = (N + 63) / 64;
    int nbg128 = (N + 127) / 128;
    int nbc   = (N + 3) / 4;

    k_pre<<<(N + 255) / 256, 256, 0, stream>>>(deg, N, lin1, wpack2, rec, E);
    // degree count (4/thr) overlapped with no-LDS layer-0 prep (hcat0/h16/r)
    k_count_h0<<<nbC + nbH0, 256, 0, stream>>>(dst, deg, rank, E, nbC,
                                               x, emb, attr_, h16, r, hcat, N);
    k_scan_part<<<nbs, 256, 0, stream>>>(deg, bsum, N);
    k_scan_out<<<nbs, 256, 0, stream>>>(deg, bsum, off, nbs, N);
    k_fill<<<nbF, 256, 0, stream>>>(src, dst, eattr, off, rank, rec, E);

    k_conv<<<nbc, 256, 0, stream>>>(off, rec, h16, r,
                                    wpack2, attl, hcat + 64, N);
    for (int l = 0; l < 2; l++) {
        k_gemm2h<<<nbg64, 256, 0, stream>>>(hcat + 64 * (l + 1),
                                            lin2 + (size_t)l * 4096, gbias + l * 64,
                                            attr_ + (l + 1) * 64, h16, r, N);
        k_conv<<<nbc, 256, 0, stream>>>(off, rec, h16, r,
                                        wpack2 + (size_t)(l + 1) * 20 * 64,
                                        attl + (l + 1) * 64,
                                        hcat + 64 * (l + 2), N);
    }
    // fused final gemm2 (layer 2) + head: h3 never touches HBM
    k_gemm2head<<<nbg128, 256, 0, stream>>>(hcat, lin2 + 2 * 4096, gbias + 128,
                                            f1w, f1b, f2w, f2b, out, N);
}

// Round 8
// 540.796 us; speedup vs baseline: 1.2235x; 1.2235x over previous
//
#include <hip/hip_runtime.h>
#include <math.h>

#define NEG 0.01f

typedef _Float16 f16;
typedef f16 h2 __attribute__((ext_vector_type(2)));

__device__ __forceinline__ float lrelu(float x) { return x > 0.f ? x : NEG * x; }

__device__ __forceinline__ h2 lrelu2(h2 x) {
    h2 y = x * (f16)0.01f;                        // v_pk_mul_f16
    return __builtin_elementwise_max(x, y);       // v_pk_max_f16 (x<0 -> 0.01x)
}

// sum across each 16-lane row via DPP; result in all 16 lanes of the row
__device__ __forceinline__ float q16_allsum(float v) {
    int x;
    x = __builtin_amdgcn_update_dpp(0, __float_as_int(v), 0xB1, 0xF, 0xF, true);  v += __int_as_float(x); // quad_perm xor1
    x = __builtin_amdgcn_update_dpp(0, __float_as_int(v), 0x4E, 0xF, 0xF, true);  v += __int_as_float(x); // quad_perm xor2
    x = __builtin_amdgcn_update_dpp(0, __float_as_int(v), 0x124, 0xF, 0xF, true); v += __int_as_float(x); // row_ror:4
    x = __builtin_amdgcn_update_dpp(0, __float_as_int(v), 0x128, 0xF, 0xF, true); v += __int_as_float(x); // row_ror:8
    return v;
}

__device__ __forceinline__ float x16_32_sum(float v) {
    v += __int_as_float(__builtin_amdgcn_ds_swizzle(__float_as_int(v), 0x401F)); // xor 16
    v += __shfl_xor(v, 32, 64);
    return v;
}

// ---------------- k_pre: zero deg + zero rec pads + pack conv weights ----
__global__ void k_pre(int* __restrict__ deg, int N,
                      const float* __restrict__ lin1, const float* __restrict__ attl,
                      uint4* __restrict__ wpack, uint4* __restrict__ rec, int E) {
    int i = blockIdx.x * blockDim.x + threadIdx.x;
    if (i < N) deg[i] = 0;
    if (i < 48) {
        int l = i >> 4, t = i & 15;
        const float* wb  = lin1 + (size_t)l * 71 * 64 + 64 * 64;  // rows 64..70
        const float* alp = attl + l * 64;
        unsigned int u[20];
#pragma unroll
        for (int j = 0; j < 4; j++) {
            int f = 4 * t + j;
            h2 a = { (f16)wb[f],       (f16)wb[64 + f]  }; u[j]      = __builtin_bit_cast(unsigned int, a);
            h2 b = { (f16)wb[128 + f], (f16)wb[192 + f] }; u[4 + j]  = __builtin_bit_cast(unsigned int, b);
            h2 c = { (f16)wb[256 + f], (f16)wb[320 + f] }; u[8 + j]  = __builtin_bit_cast(unsigned int, c);
            h2 d = { (f16)wb[384 + f], (f16)0.f         }; u[12 + j] = __builtin_bit_cast(unsigned int, d);
        }
        h2 e0 = { (f16)alp[4 * t],     (f16)alp[4 * t + 1] }; u[16] = __builtin_bit_cast(unsigned int, e0);
        h2 e1 = { (f16)alp[4 * t + 2], (f16)alp[4 * t + 3] }; u[17] = __builtin_bit_cast(unsigned int, e1);
        u[18] = 0; u[19] = 0;
        uint4* o = wpack + (size_t)i * 5;
        o[0] = make_uint4(u[0],  u[1],  u[2],  u[3]);
        o[1] = make_uint4(u[4],  u[5],  u[6],  u[7]);
        o[2] = make_uint4(u[8],  u[9],  u[10], u[11]);
        o[3] = make_uint4(u[12], u[13], u[14], u[15]);
        o[4] = make_uint4(u[16], u[17], u[18], u[19]);
    } else if (i >= 48 && i < 112) {
        rec[E + i - 48] = make_uint4(0, 0, 0, 0);   // 64 zero pads: conv overrun safe
    }
}

// fused: blocks [0,nbC): degree count (4 edges/thread); blocks [nbC,..):
// layer-0 gemm, 32-row tiles: g = emb[x]@W1a (fp16), r = emb[x].ar,
// hcat[:,0:64] = emb[x]
__global__ __launch_bounds__(256) void k_count_gemm0(
    const int* __restrict__ dst, int* __restrict__ deg, int* __restrict__ rank,
    int E, int nbC,
    const int* __restrict__ x, const float* __restrict__ emb,
    const float* __restrict__ lin1, const float* __restrict__ ar,
    f16* __restrict__ g, float* __restrict__ r_out, float* __restrict__ hcat, int N)
{
    __shared__ __align__(16) float sA[64][36];    // [K][32 rows + pad]
    __shared__ __align__(16) float sB[64 * 64];
    __shared__ float sar[64];
    int tid = threadIdx.x;
    if ((int)blockIdx.x < nbC) {
        int e = (blockIdx.x * 256 + tid) * 4;
        if (e + 3 < E) {
            int4 d = *(const int4*)(dst + e);
            int r0 = atomicAdd(&deg[d.x], 1);
            int r1 = atomicAdd(&deg[d.y], 1);
            int r2 = atomicAdd(&deg[d.z], 1);
            int r3 = atomicAdd(&deg[d.w], 1);
            *(int4*)(rank + e) = make_int4(r0, r1, r2, r3);
        } else {
            for (int k = 0; k < 4; k++)
                if (e + k < E) rank[e + k] = atomicAdd(&deg[dst[e + k]], 1);
        }
        return;
    }
    int row0 = ((int)blockIdx.x - nbC) * 32;

    {
        const float4* b4 = (const float4*)lin1;   // W1a = lin1 rows 0..63
        float4* s4 = (float4*)sB;
        for (int i = tid; i < 1024; i += 256) s4[i] = b4[i];
    }
    if (tid < 64) sar[tid] = ar[tid];

#pragma unroll
    for (int pass = 0; pass < 2; ++pass) {
        int nl = pass * 16 + (tid & 15);
        int k4 = (tid >> 4) * 4;
        int n = row0 + nl; bool ok = n < N; if (!ok) n = N - 1;
        float4 v = *(const float4*)(emb + (size_t)x[n] * 64 + k4);
        sA[k4 + 0][nl] = v.x; sA[k4 + 1][nl] = v.y;
        sA[k4 + 2][nl] = v.z; sA[k4 + 3][nl] = v.w;
        if (ok) *(float4*)(hcat + (size_t)n * 256 + k4) = v;   // hcat col block 0
    }
    __syncthreads();

    int tr = tid >> 4, tc = tid & 15;
    int r0 = tr * 2, c0 = tc * 4;
    float acc[2][4];
#pragma unroll
    for (int i = 0; i < 2; i++)
#pragma unroll
        for (int j = 0; j < 4; j++) acc[i][j] = 0.f;

#pragma unroll 4
    for (int k = 0; k < 64; ++k) {
        float4 b4 = *(const float4*)(sB + k * 64 + c0);
        float2 a0 = *(const float2*)&sA[k][r0];
#pragma unroll
        for (int j = 0; j < 4; j++) {
            float bj = (&b4.x)[j];
            acc[0][j] += a0.x * bj; acc[1][j] += a0.y * bj;
        }
    }

#pragma unroll
    for (int i = 0; i < 2; i++) {
        int n = row0 + r0 + i;
        if (n < N) {
            uint2 gw;
            gw.x = __builtin_bit_cast(unsigned int, __builtin_amdgcn_cvt_pkrtz(acc[i][0], acc[i][1]));
            gw.y = __builtin_bit_cast(unsigned int, __builtin_amdgcn_cvt_pkrtz(acc[i][2], acc[i][3]));
            *(uint2*)(g + (size_t)n * 64 + c0) = gw;
        }
    }
    if (tid < 32) {
        int n = row0 + tid;
        if (n < N) {
            float racc = 0.f;
#pragma unroll
            for (int k = 0; k < 64; k++) racc += sA[k][tid] * sar[k];
            r_out[n] = racc;
        }
    }
}

__global__ __launch_bounds__(256) void k_scan_part(const int* __restrict__ deg,
                                                   int* __restrict__ bsum, int n) {
    __shared__ int sh[256];
    int b = blockIdx.x, t = threadIdx.x;
    int i0 = b * 1024 + t * 4;
    int s = 0;
    if (i0 + 3 < n) { int4 v = *(const int4*)(deg + i0); s = v.x + v.y + v.z + v.w; }
    else { for (int k = 0; k < 4; k++) if (i0 + k < n) s += deg[i0 + k]; }
    sh[t] = s; __syncthreads();
    for (int d = 128; d > 0; d >>= 1) { if (t < d) sh[t] += sh[t + d]; __syncthreads(); }
    if (t == 0) bsum[b] = sh[0];
}

// every block redundantly scans bsum (nb<=256), then emits its 1024 offsets
__global__ __launch_bounds__(256) void k_scan_out(const int* __restrict__ deg,
                                                  const int* __restrict__ bsum,
                                                  int* __restrict__ off, int nb, int n) {
    __shared__ int sb[256];
    __shared__ int sh[256];
    int b = blockIdx.x, t = threadIdx.x;
    int v = (t < nb) ? bsum[t] : 0;
    sb[t] = v; __syncthreads();
    for (int d = 1; d < 256; d <<= 1) {
        int u = (t >= d) ? sb[t - d] : 0;
        __syncthreads(); sb[t] += u; __syncthreads();
    }
    int base = (b == 0) ? 0 : sb[b - 1];
    if (b == 0 && t == 0) off[n] = sb[255];
    int i0 = b * 1024 + t * 4;
    int4 v4 = make_int4(0, 0, 0, 0);
    if (i0 + 3 < n) v4 = *(const int4*)(deg + i0);
    else {
        v4.x = (i0     < n) ? deg[i0]     : 0;
        v4.y = (i0 + 1 < n) ? deg[i0 + 1] : 0;
        v4.z = (i0 + 2 < n) ? deg[i0 + 2] : 0;
        v4.w = (i0 + 3 < n) ? deg[i0 + 3] : 0;
    }
    int s = v4.x + v4.y + v4.z + v4.w;
    sh[t] = s; __syncthreads();
    for (int d = 1; d < 256; d <<= 1) {
        int u = (t >= d) ? sh[t - d] : 0;
        __syncthreads(); sh[t] += u; __syncthreads();
    }
    int ex = base + sh[t] - s;
    if (i0     < n) off[i0]     = ex;
    if (i0 + 1 < n) off[i0 + 1] = ex + v4.x;
    if (i0 + 2 < n) off[i0 + 2] = ex + v4.x + v4.y;
    if (i0 + 3 < n) off[i0 + 3] = ex + v4.x + v4.y + v4.z;
}

// build 16B fp16 edge records, 2 edges/thread; slot = off[dst] + rank (no atomics)
__global__ void k_fill(const int* __restrict__ src, const int* __restrict__ dst,
                       const float* __restrict__ eattr, const int* __restrict__ off,
                       const int* __restrict__ rank, uint4* __restrict__ rec, int E) {
    int e = (blockIdx.x * 256 + threadIdx.x) * 2;
    if (e >= E) return;
    bool two = (e + 1 < E);
#pragma unroll
    for (int k = 0; k < 2; k++) {
        if (k == 1 && !two) break;
        int ee = e + k;
        int slot = off[dst[ee]] + rank[ee];
        const float* ap = eattr + (size_t)ee * 7;
        float a0 = ap[0], a1 = ap[1], a2 = ap[2], a3 = ap[3], a4 = ap[4], a5 = ap[5], a6 = ap[6];
        uint4 rv;
        h2 p01 = { (f16)a0, (f16)a1 };
        h2 p23 = { (f16)a2, (f16)a3 };
        h2 p45 = { (f16)a4, (f16)a5 };
        rv.x = __builtin_bit_cast(unsigned int, p01);
        rv.y = __builtin_bit_cast(unsigned int, p23);
        rv.z = __builtin_bit_cast(unsigned int, p45);
        unsigned int a6b = (unsigned int)__builtin_bit_cast(unsigned short, (f16)a6);
        rv.w = a6b | ((unsigned int)src[ee] << 16);   // requires N < 65536
        rec[slot] = rv;
    }
}

// fused gemm2(layer l) + gemm1(layer l+1), 64-row tiles:
//   out1 = relu(agg@W2 + b) -> hc (in-place, stride 256)
//   g    = out1@W1n (fp16),  r = out1 . arn
__global__ __launch_bounds__(256) void k_gemm2g1(
    float* __restrict__ hc,
    const float* __restrict__ W2, const float* __restrict__ bias,
    const float* __restrict__ W1n, const float* __restrict__ arn,
    f16* __restrict__ g, float* __restrict__ r_out, int N)
{
    __shared__ __align__(16) float sA[64][68];
    __shared__ __align__(16) float sB[64 * 64];
    __shared__ float sar[64];
    int tid = threadIdx.x, row0 = blockIdx.x * 64;

    {
        const float4* b4 = (const float4*)W2;
        float4* s4 = (float4*)sB;
        for (int i = tid; i < 1024; i += 256) s4[i] = b4[i];
    }
    if (tid < 64) sar[tid] = arn[tid];

#pragma unroll
    for (int pass = 0; pass < 4; ++pass) {
        int nl = pass * 16 + (tid & 15);
        int k4 = (tid >> 4) * 4;
        int n = row0 + nl; if (n >= N) n = N - 1;
        float4 v = *(const float4*)(hc + (size_t)n * 256 + k4);
        sA[k4 + 0][nl] = v.x; sA[k4 + 1][nl] = v.y;
        sA[k4 + 2][nl] = v.z; sA[k4 + 3][nl] = v.w;
    }
    __syncthreads();

    int tr = tid >> 4, tc = tid & 15;
    int r0 = tr * 4, c0 = tc * 4;
    float acc[4][4];
#pragma unroll
    for (int i = 0; i < 4; i++)
#pragma unroll
        for (int j = 0; j < 4; j++) acc[i][j] = 0.f;

#pragma unroll 4
    for (int k = 0; k < 64; ++k) {
        float4 b4 = *(const float4*)(sB + k * 64 + c0);
        float4 a0 = *(const float4*)&sA[k][r0];
#pragma unroll
        for (int j = 0; j < 4; j++) {
            float bj = (&b4.x)[j];
            acc[0][j] += a0.x * bj; acc[1][j] += a0.y * bj;
            acc[2][j] += a0.z * bj; acc[3][j] += a0.w * bj;
        }
    }

    float4 bv = *(const float4*)(bias + c0);
#pragma unroll
    for (int i = 0; i < 4; i++) {
        acc[i][0] = fmaxf(acc[i][0] + bv.x, 0.f);
        acc[i][1] = fmaxf(acc[i][1] + bv.y, 0.f);
        acc[i][2] = fmaxf(acc[i][2] + bv.z, 0.f);
        acc[i][3] = fmaxf(acc[i][3] + bv.w, 0.f);
        int n = row0 + r0 + i;
        if (n < N) *(float4*)(hc + (size_t)n * 256 + c0) =
            make_float4(acc[i][0], acc[i][1], acc[i][2], acc[i][3]);
    }
    __syncthreads();   // everyone done reading sA/sB

    // restage: sB <- W1n, sA <- out1^T
    {
        const float4* b4 = (const float4*)W1n;
        float4* s4 = (float4*)sB;
        for (int i = tid; i < 1024; i += 256) s4[i] = b4[i];
    }
#pragma unroll
    for (int i = 0; i < 4; i++)
#pragma unroll
        for (int j = 0; j < 4; j++) sA[c0 + j][r0 + i] = acc[i][j];
    __syncthreads();

#pragma unroll
    for (int i = 0; i < 4; i++)
#pragma unroll
        for (int j = 0; j < 4; j++) acc[i][j] = 0.f;

#pragma unroll 4
    for (int k = 0; k < 64; ++k) {
        float4 b4 = *(const float4*)(sB + k * 64 + c0);
        float4 a0 = *(const float4*)&sA[k][r0];
#pragma unroll
        for (int j = 0; j < 4; j++) {
            float bj = (&b4.x)[j];
            acc[0][j] += a0.x * bj; acc[1][j] += a0.y * bj;
            acc[2][j] += a0.z * bj; acc[3][j] += a0.w * bj;
        }
    }

#pragma unroll
    for (int i = 0; i < 4; i++) {
        int n = row0 + r0 + i;
        if (n < N) {
            uint2 gw;
            gw.x = __builtin_bit_cast(unsigned int, __builtin_amdgcn_cvt_pkrtz(acc[i][0], acc[i][1]));
            gw.y = __builtin_bit_cast(unsigned int, __builtin_amdgcn_cvt_pkrtz(acc[i][2], acc[i][3]));
            *(uint2*)(g + (size_t)n * 64 + c0) = gw;
        }
    }
    if (tid < 64) {
        int n = row0 + tid;
        if (n < N) {
            float racc = 0.f;
#pragma unroll
            for (int k = 0; k < 64; k++) racc += sA[k][tid] * sar[k];
            r_out[n] = racc;
        }
    }
}

// ---------------- gate conv: multi-node wave, 16 edges/iter, 2-deep pipe ----
// weights loaded ONCE per wave; wave grid-strides over nodes (~6 nodes/wave).
// g-gathers use 32-bit offsets off a uniform base (saddr form):
// voff = (src<<7) | (l16<<3).  rec over-allocated +64 zeroed slots.
struct ConvW {
    h2 w01[4], w23[4], w45[4], w6_[4];
    h2 al01, al23;
};

__device__ __forceinline__ void edge_math(uint4 rv, uint2 gv, bool valid, float ri,
                                          const ConvW& W, float4& s, float& den) {
    h2 a01 = __builtin_bit_cast(h2, rv.x);
    h2 a23 = __builtin_bit_cast(h2, rv.y);
    h2 a45 = __builtin_bit_cast(h2, rv.z);
    h2 a6p = __builtin_bit_cast(h2, rv.w & 0xFFFFu);   // (a6, +0)
    h2 g01 = __builtin_bit_cast(h2, gv.x);
    h2 g23 = __builtin_bit_cast(h2, gv.y);

    float c0 = __builtin_amdgcn_fdot2(a01, W.w01[0],
               __builtin_amdgcn_fdot2(a23, W.w23[0],
               __builtin_amdgcn_fdot2(a45, W.w45[0],
               __builtin_amdgcn_fdot2(a6p, W.w6_[0], 0.f, false), false), false), false);
    float c1 = __builtin_amdgcn_fdot2(a01, W.w01[1],
               __builtin_amdgcn_fdot2(a23, W.w23[1],
               __builtin_amdgcn_fdot2(a45, W.w45[1],
               __builtin_amdgcn_fdot2(a6p, W.w6_[1], 0.f, false), false), false), false);
    float c2 = __builtin_amdgcn_fdot2(a01, W.w01[2],
               __builtin_amdgcn_fdot2(a23, W.w23[2],
               __builtin_amdgcn_fdot2(a45, W.w45[2],
               __builtin_amdgcn_fdot2(a6p, W.w6_[2], 0.f, false), false), false), false);
    float c3 = __builtin_amdgcn_fdot2(a01, W.w01[3],
               __builtin_amdgcn_fdot2(a23, W.w23[3],
               __builtin_amdgcn_fdot2(a45, W.w45[3],
               __builtin_amdgcn_fdot2(a6p, W.w6_[3], 0.f, false), false), false), false);

    h2 x01 = lrelu2(g01 + __builtin_amdgcn_cvt_pkrtz(c0, c1));
    h2 x23 = lrelu2(g23 + __builtin_amdgcn_cvt_pkrtz(c2, c3));
    float p = __builtin_amdgcn_fdot2(x01, W.al01,
              __builtin_amdgcn_fdot2(x23, W.al23, 0.f, false), false);
    p = q16_allsum(p);
    float alpha = lrelu(p + ri);
    float w = valid ? __expf(alpha) : 0.f;   // |alpha| bounded: no max-subtraction
    s.x += w * (float)x01.x; s.y += w * (float)x01.y;
    s.z += w * (float)x23.x; s.w += w * (float)x23.y;
    den += w;
}

__global__ __launch_bounds__(256) void k_conv(
    const int* __restrict__ off, const uint4* __restrict__ rec,
    const f16* __restrict__ g, const float* __restrict__ r,
    const uint4* __restrict__ wpack, float* __restrict__ aggdst,
    int N, int nw)
{
    int lane = threadIdx.x & 63;
    int q = lane >> 4, l16 = lane & 15;
    int wid = blockIdx.x * 4 + (threadIdx.x >> 6);

    ConvW W;
    {
        const uint4* wp = wpack + l16 * 5;
        uint4 v0 = wp[0], v1 = wp[1], v2 = wp[2], v3 = wp[3], v4 = wp[4];
        W.w01[0] = __builtin_bit_cast(h2, v0.x); W.w01[1] = __builtin_bit_cast(h2, v0.y);
        W.w01[2] = __builtin_bit_cast(h2, v0.z); W.w01[3] = __builtin_bit_cast(h2, v0.w);
        W.w23[0] = __builtin_bit_cast(h2, v1.x); W.w23[1] = __builtin_bit_cast(h2, v1.y);
        W.w23[2] = __builtin_bit_cast(h2, v1.z); W.w23[3] = __builtin_bit_cast(h2, v1.w);
        W.w45[0] = __builtin_bit_cast(h2, v2.x); W.w45[1] = __builtin_bit_cast(h2, v2.y);
        W.w45[2] = __builtin_bit_cast(h2, v2.z); W.w45[3] = __builtin_bit_cast(h2, v2.w);
        W.w6_[0] = __builtin_bit_cast(h2, v3.x); W.w6_[1] = __builtin_bit_cast(h2, v3.y);
        W.w6_[2] = __builtin_bit_cast(h2, v3.z); W.w6_[3] = __builtin_bit_cast(h2, v3.w);
        W.al01   = __builtin_bit_cast(h2, v4.x); W.al23   = __builtin_bit_cast(h2, v4.y);
    }

    const char* gbase = (const char*)g;
    unsigned lofs = (unsigned)(l16 << 3);

    for (int node = wid; node < N; node += nw) {
        float ri = r[node];
        int e0 = off[node], e1 = off[node + 1];

        float4 s = make_float4(0.f, 0.f, 0.f, 0.f);
        float den = 0.f;
        if (e0 < e1) {
            const uint4* rp = rec + e0 + q;
            // iter-0 records (unconditional: rec padded+zeroed past E)
            uint4 ra = rp[0], rb = rp[4], rc = rp[8], rd = rp[12];
            // iter-0 g rows (32-bit voffset from uniform base)
            uint2 ga = *(const uint2*)(gbase + (((ra.w >> 16) << 7) | lofs));
            uint2 gb = *(const uint2*)(gbase + (((rb.w >> 16) << 7) | lofs));
            uint2 gc = *(const uint2*)(gbase + (((rc.w >> 16) << 7) | lofs));
            uint2 gd = *(const uint2*)(gbase + (((rd.w >> 16) << 7) | lofs));
            // iter-1 records
            uint4 na = rp[16], nb = rp[20], nc = rp[24], nd = rp[28];
            for (int e = e0; e < e1; e += 16) {
                // issue next-iter g gathers (records already resident)
                uint2 gna = *(const uint2*)(gbase + (((na.w >> 16) << 7) | lofs));
                uint2 gnb = *(const uint2*)(gbase + (((nb.w >> 16) << 7) | lofs));
                uint2 gnc = *(const uint2*)(gbase + (((nc.w >> 16) << 7) | lofs));
                uint2 gnd = *(const uint2*)(gbase + (((nd.w >> 16) << 7) | lofs));
                // issue iter+2 record loads (base+imm offsets only)
                rp += 16;
                uint4 ma = rp[16], mb = rp[20], mc = rp[24], md = rp[28];
                bool va = (e + q)      < e1, vb = (e + 4 + q)  < e1;
                bool vc = (e + 8 + q)  < e1, vd = (e + 12 + q) < e1;
                edge_math(ra, ga, va, ri, W, s, den);
                edge_math(rb, gb, vb, ri, W, s, den);
                edge_math(rc, gc, vc, ri, W, s, den);
                edge_math(rd, gd, vd, ri, W, s, den);
                ra = na; rb = nb; rc = nc; rd = nd;
                ga = gna; gb = gnb; gc = gnc; gd = gnd;
                na = ma; nb = mb; nc = mc; nd = md;
            }
        }
        s.x = x16_32_sum(s.x); s.y = x16_32_sum(s.y);
        s.z = x16_32_sum(s.z); s.w = x16_32_sum(s.w);
        den = x16_32_sum(den);
        float inv = 1.f / (den + 1e-16f);
        if (q == 0) {
            float4 o = make_float4(s.x * inv, s.y * inv, s.z * inv, s.w * inv);
            *(float4*)(aggdst + (size_t)node * 256 + 4 * l16) = o;
        }
    }
}

// ---------------- fused final gemm2 (layer 2) + head ----------------
// h3 = relu(agg2@W2 + b) stays in LDS (never written to hcat);
// head threads remapped pairwise (row=tid>>1, half=tid&1) -> shfl_xor combine.
__global__ __launch_bounds__(256) void k_gemm2head(
    const float* __restrict__ hcat,
    const float* __restrict__ W2, const float* __restrict__ bias,
    const float* __restrict__ f1w, const float* __restrict__ f1b,
    const float* __restrict__ f2w, const float* __restrict__ f2b,
    float* __restrict__ out, int N)
{
    __shared__ __align__(16) float sA[64][130];   // gemm A staging, then sO[128][65]
    __shared__ __align__(16) float sBW[5120];     // W2 (4096), then f1w (5120)
    int tid = threadIdx.x, row0 = blockIdx.x * 128;

    {
        const float4* b4 = (const float4*)W2;
        float4* s4 = (float4*)sBW;
        for (int i = tid; i < 1024; i += 256) s4[i] = b4[i];
    }
#pragma unroll
    for (int pass = 0; pass < 8; ++pass) {
        int nl = pass * 16 + (tid & 15);
        int k4 = (tid >> 4) * 4;
        int n = row0 + nl; if (n >= N) n = N - 1;
        float4 v = *(const float4*)(hcat + (size_t)n * 256 + 192 + k4);
        sA[k4 + 0][nl] = v.x; sA[k4 + 1][nl] = v.y;
        sA[k4 + 2][nl] = v.z; sA[k4 + 3][nl] = v.w;
    }
    __syncthreads();

    int tr = tid >> 4, tc = tid & 15;
    int r0 = tr * 8, c0 = tc * 4;
    float acc[8][4];
#pragma unroll
    for (int i = 0; i < 8; i++)
#pragma unroll
        for (int j = 0; j < 4; j++) acc[i][j] = 0.f;

#pragma unroll 4
    for (int k = 0; k < 64; ++k) {
        float4 b4 = *(const float4*)(sBW + k * 64 + c0);
        float4 a0 = *(const float4*)&sA[k][r0];
        float4 a1 = *(const float4*)&sA[k][r0 + 4];
#pragma unroll
        for (int j = 0; j < 4; j++) {
            float bj = (&b4.x)[j];
            acc[0][j] += a0.x * bj; acc[1][j] += a0.y * bj;
            acc[2][j] += a0.z * bj; acc[3][j] += a0.w * bj;
            acc[4][j] += a1.x * bj; acc[5][j] += a1.y * bj;
            acc[6][j] += a1.z * bj; acc[7][j] += a1.w * bj;
        }
    }

    // issue f1w loads early (write to LDS only after the sync)
    float4 fw[5];
    {
        const float4* w4 = (const float4*)f1w;
#pragma unroll
        for (int i2 = 0; i2 < 5; i2++) fw[i2] = w4[tid + i2 * 256];
    }
    __syncthreads();   // everyone done reading sA/sBW

    float* sO = &sA[0][0];          // [128][65] = 8320 = 64*130 floats exactly
    float4 bv = *(const float4*)(bias + c0);
#pragma unroll
    for (int i = 0; i < 8; i++) {
        acc[i][0] = fmaxf(acc[i][0] + bv.x, 0.f);
        acc[i][1] = fmaxf(acc[i][1] + bv.y, 0.f);
        acc[i][2] = fmaxf(acc[i][2] + bv.z, 0.f);
        acc[i][3] = fmaxf(acc[i][3] + bv.w, 0.f);
        int rr = r0 + i;
        sO[rr * 65 + c0 + 0] = acc[i][0];
        sO[rr * 65 + c0 + 1] = acc[i][1];
        sO[rr * 65 + c0 + 2] = acc[i][2];
        sO[rr * 65 + c0 + 3] = acc[i][3];
    }
    {
        float4* sw4 = (float4*)sBW;
#pragma unroll
        for (int i2 = 0; i2 < 5; i2++) sw4[tid + i2 * 256] = fw[i2];
    }
    __syncthreads();

    // head: row = tid>>1, half = tid&1 (pair lanes adjacent -> shfl combine)
    int rloc = tid >> 1;
    int half = tid & 1;
    int n = row0 + rloc;
    int nn = (n < N) ? n : N - 1;
    float z[20];
#pragma unroll
    for (int j = 0; j < 20; j++) z[j] = 0.f;
    const float4* hr = (const float4*)(hcat + (size_t)nn * 256);
    if (half == 0) {
        for (int k4 = 0; k4 < 32; k4++) {
            float4 h = hr[k4];
            const float* wr = sBW + k4 * 80;
#pragma unroll
            for (int j = 0; j < 20; j++)
                z[j] += h.x * wr[j] + h.y * wr[20 + j] + h.z * wr[40 + j] + h.w * wr[60 + j];
        }
    } else {
        for (int k4 = 32; k4 < 48; k4++) {
            float4 h = hr[k4];
            const float* wr = sBW + k4 * 80;
#pragma unroll
            for (int j = 0; j < 20; j++)
                z[j] += h.x * wr[j] + h.y * wr[20 + j] + h.z * wr[40 + j] + h.w * wr[60 + j];
        }
        for (int k = 0; k < 64; k += 2) {
            float hx = sO[rloc * 65 + k], hy = sO[rloc * 65 + k + 1];
            const float* wr = sBW + (192 + k) * 20;
#pragma unroll
            for (int j = 0; j < 20; j++)
                z[j] += hx * wr[j] + hy * wr[20 + j];
        }
    }
    // combine halves: lanes (2i, 2i+1) hold the two partials of row i
#pragma unroll
    for (int j = 0; j < 20; j++) z[j] += __shfl_xor(z[j], 1, 64);
    if (half == 0 && n < N) {
        float o = f2b[0];
#pragma unroll
        for (int j = 0; j < 20; j++) {
            float zj = z[j] + f1b[j];
            o += fmaxf(zj, 0.f) * f2w[j];
        }
        out[n] = 1.f / (1.f + __expf(-o));
    }
}

extern "C" void kernel_launch(void* const* d_in, const int* in_sizes, int n_in,
                              void* d_out, int out_size, void* d_ws, size_t ws_size,
                              hipStream_t stream) {
    const int*   x     = (const int*)d_in[0];
    const int*   eidx  = (const int*)d_in[1];
    const float* eattr = (const float*)d_in[2];
    const float* emb   = (const float*)d_in[3];
    const float* lin1  = (const float*)d_in[4];   // [3,71,64]
    const float* attl  = (const float*)d_in[5];   // [3,64]
    const float* attr_ = (const float*)d_in[6];   // [3,64]
    const float* lin2  = (const float*)d_in[7];   // [3,64,64]
    const float* gbias = (const float*)d_in[8];   // [3,64]
    const float* f1w   = (const float*)d_in[9];   // [256,20]
    const float* f1b   = (const float*)d_in[10];
    const float* f2w   = (const float*)d_in[11];
    const float* f2b   = (const float*)d_in[12];
    float* out = (float*)d_out;

    int N = in_sizes[0];
    int E = in_sizes[1] / 2;
    const int* src = eidx;
    const int* dst = eidx + E;

    // workspace carve (256B aligned)
    char* p = (char*)d_ws;
    auto alloc = [&](size_t bytes) { void* q = (void*)p; p += (bytes + 255) & ~(size_t)255; return q; };
    float* hcat = (float*)alloc((size_t)N * 256 * 4);
    f16*   g    = (f16*)alloc((size_t)N * 64 * 2);
    float* r    = (float*)alloc((size_t)N * 4);
    int*   off  = (int*)alloc((size_t)(N + 1) * 4);
    int*   deg  = (int*)alloc((size_t)N * 4);
    int*   rank = (int*)alloc((size_t)E * 4);
    int*   bsum = (int*)alloc(256 * 4);
    uint4* rec  = (uint4*)alloc((size_t)(E + 64) * 16);   // +64 zeroed pad slots
    uint4* wpack = (uint4*)alloc((size_t)48 * 5 * 16);    // packed conv weights

    int nbs   = (N + 1023) / 1024;           // 49 scan blocks (<=256)
    int nbC   = ((E + 3) / 4 + 255) / 256;   // count blocks, 4 edges/thread
    int nbG0  = (N + 31) / 32;               // layer-0 gemm tiles (32-row)
    int nbF   = ((E + 1) / 2 + 255) / 256;   // fill blocks, 2 edges/thread
    int nbg64 = (N + 63) / 64;
    int nbg128 = (N + 127) / 128;
    int nbc   = (N + 3) / 4; if (nbc > 2048) nbc = 2048;   // multi-node waves
    int nw    = nbc * 4;

    k_pre<<<(N + 255) / 256, 256, 0, stream>>>(deg, N, lin1, attl, wpack, rec, E);
    // degree count (4/thr) overlapped with layer-0 gemm (32-row tiles)
    k_count_gemm0<<<nbC + nbG0, 256, 0, stream>>>(dst, deg, rank, E, nbC,
                                                  x, emb, lin1, attr_, g, r, hcat, N);
    k_scan_part<<<nbs, 256, 0, stream>>>(deg, bsum, N);
    k_scan_out<<<nbs, 256, 0, stream>>>(deg, bsum, off, nbs, N);
    k_fill<<<nbF, 256, 0, stream>>>(src, dst, eattr, off, rank, rec, E);

    k_conv<<<nbc, 256, 0, stream>>>(off, rec, g, r, wpack, hcat + 64, N, nw);
    for (int l = 0; l < 2; l++) {
        k_gemm2g1<<<nbg64, 256, 0, stream>>>(hcat + 64 * (l + 1),
                                             lin2 + (size_t)l * 4096, gbias + l * 64,
                                             lin1 + (size_t)(l + 1) * 71 * 64,
                                             attr_ + (l + 1) * 64, g, r, N);
        k_conv<<<nbc, 256, 0, stream>>>(off, rec, g, r,
                                        wpack + (size_t)(l + 1) * 80,
                                        hcat + 64 * (l + 2), N, nw);
    }
    // fused final gemm2 (layer 2) + head: h3 never touches HBM
    k_gemm2head<<<nbg128, 256, 0, stream>>>(hcat, lin2 + 2 * 4096, gbias + 128,
                                            f1w, f1b, f2w, f2b, out, N);
}

// Round 9
// 499.992 us; speedup vs baseline: 1.3234x; 1.0816x over previous
//
#include <hip/hip_runtime.h>
#include <math.h>

#define NEG 0.01f

typedef _Float16 f16;
typedef f16 h2 __attribute__((ext_vector_type(2)));

__device__ __forceinline__ float lrelu(float x) { return x > 0.f ? x : NEG * x; }

__device__ __forceinline__ h2 lrelu2(h2 x) {
    h2 y = x * (f16)0.01f;                        // v_pk_mul_f16
    return __builtin_elementwise_max(x, y);       // v_pk_max_f16 (x<0 -> 0.01x)
}

// sum across each 16-lane row via DPP; result in all 16 lanes of the row
__device__ __forceinline__ float q16_allsum(float v) {
    int x;
    x = __builtin_amdgcn_update_dpp(0, __float_as_int(v), 0xB1, 0xF, 0xF, true);  v += __int_as_float(x); // quad_perm xor1
    x = __builtin_amdgcn_update_dpp(0, __float_as_int(v), 0x4E, 0xF, 0xF, true);  v += __int_as_float(x); // quad_perm xor2
    x = __builtin_amdgcn_update_dpp(0, __float_as_int(v), 0x124, 0xF, 0xF, true); v += __int_as_float(x); // row_ror:4
    x = __builtin_amdgcn_update_dpp(0, __float_as_int(v), 0x128, 0xF, 0xF, true); v += __int_as_float(x); // row_ror:8
    return v;
}

__device__ __forceinline__ float x16_32_sum(float v) {
    v += __int_as_float(__builtin_amdgcn_ds_swizzle(__float_as_int(v), 0x401F)); // xor 16
    v += __shfl_xor(v, 32, 64);
    return v;
}

// ---------------- CSR build ----------------
// k_zero also packs the per-layer conv weights (fp16 ConvW layout) into ws:
// slot i in [0,48): layer l=i>>4, lane-slot t=i&15; 5 x uint4 per slot.
__global__ void k_zero(int* __restrict__ deg, int n,
                       const float* __restrict__ lin1, const float* __restrict__ attl,
                       uint4* __restrict__ wpack) {
    int i = blockIdx.x * blockDim.x + threadIdx.x;
    if (i < n) deg[i] = 0;
    if (i < 48) {
        int l = i >> 4, t = i & 15;
        const float* wb  = lin1 + (size_t)l * 71 * 64 + 64 * 64;  // rows 64..70
        const float* alp = attl + l * 64;
        unsigned int u[20];
#pragma unroll
        for (int j = 0; j < 4; j++) {
            int f = 4 * t + j;
            h2 a = { (f16)wb[f],       (f16)wb[64 + f]  }; u[j]      = __builtin_bit_cast(unsigned int, a);
            h2 b = { (f16)wb[128 + f], (f16)wb[192 + f] }; u[4 + j]  = __builtin_bit_cast(unsigned int, b);
            h2 c = { (f16)wb[256 + f], (f16)wb[320 + f] }; u[8 + j]  = __builtin_bit_cast(unsigned int, c);
            h2 d = { (f16)wb[384 + f], (f16)0.f         }; u[12 + j] = __builtin_bit_cast(unsigned int, d);
        }
        h2 e0 = { (f16)alp[4 * t],     (f16)alp[4 * t + 1] }; u[16] = __builtin_bit_cast(unsigned int, e0);
        h2 e1 = { (f16)alp[4 * t + 2], (f16)alp[4 * t + 3] }; u[17] = __builtin_bit_cast(unsigned int, e1);
        u[18] = 0; u[19] = 0;
        uint4* o = wpack + (size_t)i * 5;
        o[0] = make_uint4(u[0],  u[1],  u[2],  u[3]);
        o[1] = make_uint4(u[4],  u[5],  u[6],  u[7]);
        o[2] = make_uint4(u[8],  u[9],  u[10], u[11]);
        o[3] = make_uint4(u[12], u[13], u[14], u[15]);
        o[4] = make_uint4(u[16], u[17], u[18], u[19]);
    }
}

// fused: blocks [0,nbCnt) do edge-degree count (rank return); blocks [nbCnt,..)
// do the layer-0 gemm in 16-ROW tiles (small LDS ~21KB -> ~7 blocks/CU so the
// count branch gets ~28 waves/CU of occupancy):
//   g = emb[x]@W1a (fp16), r = emb[x].ar, hcat[:,0:64] = emb[x]
__global__ __launch_bounds__(256) void k_count_gemm(
    const int* __restrict__ dst, int* __restrict__ deg, int* __restrict__ rank,
    int E, int nbCnt,
    const int* __restrict__ x, const float* __restrict__ emb,
    const float* __restrict__ B, const float* __restrict__ ar,
    f16* __restrict__ g, float* __restrict__ r_out, float* __restrict__ hcat, int N)
{
    __shared__ __align__(16) float sA[64][20];   // [K][16 rows + pad]
    __shared__ __align__(16) float sB[64 * 64];
    __shared__ float sar[64];
    if ((int)blockIdx.x < nbCnt) {
        int e = blockIdx.x * 256 + threadIdx.x;
        if (e < E) rank[e] = atomicAdd(&deg[dst[e]], 1);
        return;
    }
    int tid = threadIdx.x;
    int row0 = ((int)blockIdx.x - nbCnt) * 16;

    {
        const float4* b4 = (const float4*)B;
        float4* s4 = (float4*)sB;
        for (int i = tid; i < 1024; i += 256) s4[i] = b4[i];
    }
    if (tid < 64) sar[tid] = ar[tid];

    {
        int nl = tid & 15;
        int k4 = (tid >> 4) * 4;
        int n = row0 + nl; bool ok = n < N; if (!ok) n = N - 1;
        float4 v = *(const float4*)(emb + (size_t)x[n] * 64 + k4);
        sA[k4 + 0][nl] = v.x; sA[k4 + 1][nl] = v.y;
        sA[k4 + 2][nl] = v.z; sA[k4 + 3][nl] = v.w;
        if (ok) *(float4*)(hcat + (size_t)n * 256 + k4) = v;   // hcat col block 0
    }
    __syncthreads();

    int tr = tid >> 4, tc = tid & 15;
    int c0 = tc * 4;
    float acc[4] = {0.f, 0.f, 0.f, 0.f};

#pragma unroll 8
    for (int k = 0; k < 64; ++k) {
        float4 b4 = *(const float4*)(sB + k * 64 + c0);
        float a = sA[k][tr];
        acc[0] += a * b4.x; acc[1] += a * b4.y;
        acc[2] += a * b4.z; acc[3] += a * b4.w;
    }

    {
        int n = row0 + tr;
        if (n < N) {
            uint2 gw;
            gw.x = __builtin_bit_cast(unsigned int, __builtin_amdgcn_cvt_pkrtz(acc[0], acc[1]));
            gw.y = __builtin_bit_cast(unsigned int, __builtin_amdgcn_cvt_pkrtz(acc[2], acc[3]));
            *(uint2*)(g + (size_t)n * 64 + c0) = gw;
        }
    }
    if (tid < 16) {
        int n = row0 + tid;
        if (n < N) {
            float racc = 0.f;
#pragma unroll
            for (int k = 0; k < 64; k++) racc += sA[k][tid] * sar[k];
            r_out[n] = racc;
        }
    }
}

__global__ __launch_bounds__(256) void k_scan_part(const int* __restrict__ deg,
                                                   int* __restrict__ bsum, int n) {
    __shared__ int sh[256];
    int b = blockIdx.x, t = threadIdx.x;
    int i0 = b * 1024 + t * 4;
    int s = 0;
    if (i0 + 3 < n) { int4 v = *(const int4*)(deg + i0); s = v.x + v.y + v.z + v.w; }
    else { for (int k = 0; k < 4; k++) if (i0 + k < n) s += deg[i0 + k]; }
    sh[t] = s; __syncthreads();
    for (int d = 128; d > 0; d >>= 1) { if (t < d) sh[t] += sh[t + d]; __syncthreads(); }
    if (t == 0) bsum[b] = sh[0];
}

// every block redundantly scans bsum (nb<=256), then emits its 1024 offsets
__global__ __launch_bounds__(256) void k_scan_out(const int* __restrict__ deg,
                                                  const int* __restrict__ bsum,
                                                  int* __restrict__ off, int nb, int n) {
    __shared__ int sb[256];
    __shared__ int sh[256];
    int b = blockIdx.x, t = threadIdx.x;
    int v = (t < nb) ? bsum[t] : 0;
    sb[t] = v; __syncthreads();
    for (int d = 1; d < 256; d <<= 1) {
        int u = (t >= d) ? sb[t - d] : 0;
        __syncthreads(); sb[t] += u; __syncthreads();
    }
    int base = (b == 0) ? 0 : sb[b - 1];
    if (b == 0 && t == 0) off[n] = sb[255];
    int i0 = b * 1024 + t * 4;
    int4 v4 = make_int4(0, 0, 0, 0);
    if (i0 + 3 < n) v4 = *(const int4*)(deg + i0);
    else {
        v4.x = (i0     < n) ? deg[i0]     : 0;
        v4.y = (i0 + 1 < n) ? deg[i0 + 1] : 0;
        v4.z = (i0 + 2 < n) ? deg[i0 + 2] : 0;
        v4.w = (i0 + 3 < n) ? deg[i0 + 3] : 0;
    }
    int s = v4.x + v4.y + v4.z + v4.w;
    sh[t] = s; __syncthreads();
    for (int d = 1; d < 256; d <<= 1) {
        int u = (t >= d) ? sh[t - d] : 0;
        __syncthreads(); sh[t] += u; __syncthreads();
    }
    int ex = base + sh[t] - s;
    if (i0     < n) off[i0]     = ex;
    if (i0 + 1 < n) off[i0 + 1] = ex + v4.x;
    if (i0 + 2 < n) off[i0 + 2] = ex + v4.x + v4.y;
    if (i0 + 3 < n) off[i0 + 3] = ex + v4.x + v4.y + v4.z;
}

// build 16B fp16 edge records; slot = off[dst] + rank (no atomics)
__global__ void k_fill(const int* __restrict__ src, const int* __restrict__ dst,
                       const float* __restrict__ eattr, const int* __restrict__ off,
                       const int* __restrict__ rank, uint4* __restrict__ rec, int E) {
    int e = blockIdx.x * 256 + threadIdx.x;
    if (e >= E) return;
    int slot = off[dst[e]] + rank[e];
    const float* ap = eattr + (size_t)e * 7;
    float a0 = ap[0], a1 = ap[1], a2 = ap[2], a3 = ap[3], a4 = ap[4], a5 = ap[5], a6 = ap[6];
    uint4 rv;
    h2 p01 = { (f16)a0, (f16)a1 };
    h2 p23 = { (f16)a2, (f16)a3 };
    h2 p45 = { (f16)a4, (f16)a5 };
    rv.x = __builtin_bit_cast(unsigned int, p01);
    rv.y = __builtin_bit_cast(unsigned int, p23);
    rv.z = __builtin_bit_cast(unsigned int, p45);
    unsigned int a6b = (unsigned int)__builtin_bit_cast(unsigned short, (f16)a6);
    rv.w = a6b | ((unsigned int)src[e] << 16);   // requires N < 65536
    rec[slot] = rv;
}

// fused gemm2(layer l) + gemm1(layer l+1), 64-row tiles:
//   out1 = relu(agg@W2 + b) -> hc (in-place, stride 256)
//   g    = out1@W1n (fp16),  r = out1 . arn
__global__ __launch_bounds__(256) void k_gemm2g1(
    float* __restrict__ hc,
    const float* __restrict__ W2, const float* __restrict__ bias,
    const float* __restrict__ W1n, const float* __restrict__ arn,
    f16* __restrict__ g, float* __restrict__ r_out, int N)
{
    __shared__ __align__(16) float sA[64][68];
    __shared__ __align__(16) float sB[64 * 64];
    __shared__ float sar[64];
    int tid = threadIdx.x, row0 = blockIdx.x * 64;

    {
        const float4* b4 = (const float4*)W2;
        float4* s4 = (float4*)sB;
        for (int i = tid; i < 1024; i += 256) s4[i] = b4[i];
    }
    if (tid < 64) sar[tid] = arn[tid];

#pragma unroll
    for (int pass = 0; pass < 4; ++pass) {
        int nl = pass * 16 + (tid & 15);
        int k4 = (tid >> 4) * 4;
        int n = row0 + nl; if (n >= N) n = N - 1;
        float4 v = *(const float4*)(hc + (size_t)n * 256 + k4);
        sA[k4 + 0][nl] = v.x; sA[k4 + 1][nl] = v.y;
        sA[k4 + 2][nl] = v.z; sA[k4 + 3][nl] = v.w;
    }
    __syncthreads();

    int tr = tid >> 4, tc = tid & 15;
    int r0 = tr * 4, c0 = tc * 4;
    float acc[4][4];
#pragma unroll
    for (int i = 0; i < 4; i++)
#pragma unroll
        for (int j = 0; j < 4; j++) acc[i][j] = 0.f;

#pragma unroll 4
    for (int k = 0; k < 64; ++k) {
        float4 b4 = *(const float4*)(sB + k * 64 + c0);
        float4 a0 = *(const float4*)&sA[k][r0];
#pragma unroll
        for (int j = 0; j < 4; j++) {
            float bj = (&b4.x)[j];
            acc[0][j] += a0.x * bj; acc[1][j] += a0.y * bj;
            acc[2][j] += a0.z * bj; acc[3][j] += a0.w * bj;
        }
    }

    float4 bv = *(const float4*)(bias + c0);
#pragma unroll
    for (int i = 0; i < 4; i++) {
        acc[i][0] = fmaxf(acc[i][0] + bv.x, 0.f);
        acc[i][1] = fmaxf(acc[i][1] + bv.y, 0.f);
        acc[i][2] = fmaxf(acc[i][2] + bv.z, 0.f);
        acc[i][3] = fmaxf(acc[i][3] + bv.w, 0.f);
        int n = row0 + r0 + i;
        if (n < N) *(float4*)(hc + (size_t)n * 256 + c0) =
            make_float4(acc[i][0], acc[i][1], acc[i][2], acc[i][3]);
    }
    __syncthreads();   // everyone done reading sA/sB

    // restage: sB <- W1n, sA <- out1^T
    {
        const float4* b4 = (const float4*)W1n;
        float4* s4 = (float4*)sB;
        for (int i = tid; i < 1024; i += 256) s4[i] = b4[i];
    }
#pragma unroll
    for (int i = 0; i < 4; i++)
#pragma unroll
        for (int j = 0; j < 4; j++) sA[c0 + j][r0 + i] = acc[i][j];
    __syncthreads();

#pragma unroll
    for (int i = 0; i < 4; i++)
#pragma unroll
        for (int j = 0; j < 4; j++) acc[i][j] = 0.f;

#pragma unroll 4
    for (int k = 0; k < 64; ++k) {
        float4 b4 = *(const float4*)(sB + k * 64 + c0);
        float4 a0 = *(const float4*)&sA[k][r0];
#pragma unroll
        for (int j = 0; j < 4; j++) {
            float bj = (&b4.x)[j];
            acc[0][j] += a0.x * bj; acc[1][j] += a0.y * bj;
            acc[2][j] += a0.z * bj; acc[3][j] += a0.w * bj;
        }
    }

#pragma unroll
    for (int i = 0; i < 4; i++) {
        int n = row0 + r0 + i;
        if (n < N) {
            uint2 gw;
            gw.x = __builtin_bit_cast(unsigned int, __builtin_amdgcn_cvt_pkrtz(acc[i][0], acc[i][1]));
            gw.y = __builtin_bit_cast(unsigned int, __builtin_amdgcn_cvt_pkrtz(acc[i][2], acc[i][3]));
            *(uint2*)(g + (size_t)n * 64 + c0) = gw;
        }
    }
    if (tid < 64) {
        int n = row0 + tid;
        if (n < N) {
            float racc = 0.f;
#pragma unroll
            for (int k = 0; k < 64; k++) racc += sA[k][tid] * sar[k];
            r_out[n] = racc;
        }
    }
}

// ---------------- gate conv: wave/node, 16 edges/iter, fdot2 fp16 math ----
struct ConvW {
    h2 w01[4], w23[4], w45[4], w6_[4];
    h2 al01, al23;
};

__device__ __forceinline__ void edge_math(uint4 rv, uint2 gv, bool valid, float ri,
                                          const ConvW& W, float4& s, float& den) {
    h2 a01 = __builtin_bit_cast(h2, rv.x);
    h2 a23 = __builtin_bit_cast(h2, rv.y);
    h2 a45 = __builtin_bit_cast(h2, rv.z);
    h2 a6p = __builtin_bit_cast(h2, rv.w & 0xFFFFu);   // (a6, +0)
    h2 g01 = __builtin_bit_cast(h2, gv.x);
    h2 g23 = __builtin_bit_cast(h2, gv.y);

    float c0 = __builtin_amdgcn_fdot2(a01, W.w01[0],
               __builtin_amdgcn_fdot2(a23, W.w23[0],
               __builtin_amdgcn_fdot2(a45, W.w45[0],
               __builtin_amdgcn_fdot2(a6p, W.w6_[0], 0.f, false), false), false), false);
    float c1 = __builtin_amdgcn_fdot2(a01, W.w01[1],
               __builtin_amdgcn_fdot2(a23, W.w23[1],
               __builtin_amdgcn_fdot2(a45, W.w45[1],
               __builtin_amdgcn_fdot2(a6p, W.w6_[1], 0.f, false), false), false), false);
    float c2 = __builtin_amdgcn_fdot2(a01, W.w01[2],
               __builtin_amdgcn_fdot2(a23, W.w23[2],
               __builtin_amdgcn_fdot2(a45, W.w45[2],
               __builtin_amdgcn_fdot2(a6p, W.w6_[2], 0.f, false), false), false), false);
    float c3 = __builtin_amdgcn_fdot2(a01, W.w01[3],
               __builtin_amdgcn_fdot2(a23, W.w23[3],
               __builtin_amdgcn_fdot2(a45, W.w45[3],
               __builtin_amdgcn_fdot2(a6p, W.w6_[3], 0.f, false), false), false), false);

    h2 x01 = lrelu2(g01 + __builtin_amdgcn_cvt_pkrtz(c0, c1));
    h2 x23 = lrelu2(g23 + __builtin_amdgcn_cvt_pkrtz(c2, c3));
    float p = __builtin_amdgcn_fdot2(x01, W.al01,
              __builtin_amdgcn_fdot2(x23, W.al23, 0.f, false), false);
    p = q16_allsum(p);
    float alpha = lrelu(p + ri);
    float w = valid ? __expf(alpha) : 0.f;   // |alpha| bounded: no max-subtraction
    s.x += w * (float)x01.x; s.y += w * (float)x01.y;
    s.z += w * (float)x23.x; s.w += w * (float)x23.y;
    den += w;
}

__global__ __launch_bounds__(256) void k_conv(
    const int* __restrict__ off, const uint4* __restrict__ rec,
    const f16* __restrict__ g, const float* __restrict__ r,
    const uint4* __restrict__ wpack, float* __restrict__ aggdst, int N)
{
    int lane = threadIdx.x & 63;
    int wid  = threadIdx.x >> 6;
    int node = blockIdx.x * 4 + wid;
    if (node >= N) return;                 // wave-uniform exit, no barriers
    int q = lane >> 4, l16 = lane & 15;

    ConvW W;
    {
        const uint4* wp = wpack + l16 * 5;
        uint4 v0 = wp[0], v1 = wp[1], v2 = wp[2], v3 = wp[3], v4 = wp[4];
        W.w01[0] = __builtin_bit_cast(h2, v0.x); W.w01[1] = __builtin_bit_cast(h2, v0.y);
        W.w01[2] = __builtin_bit_cast(h2, v0.z); W.w01[3] = __builtin_bit_cast(h2, v0.w);
        W.w23[0] = __builtin_bit_cast(h2, v1.x); W.w23[1] = __builtin_bit_cast(h2, v1.y);
        W.w23[2] = __builtin_bit_cast(h2, v1.z); W.w23[3] = __builtin_bit_cast(h2, v1.w);
        W.w45[0] = __builtin_bit_cast(h2, v2.x); W.w45[1] = __builtin_bit_cast(h2, v2.y);
        W.w45[2] = __builtin_bit_cast(h2, v2.z); W.w45[3] = __builtin_bit_cast(h2, v2.w);
        W.w6_[0] = __builtin_bit_cast(h2, v3.x); W.w6_[1] = __builtin_bit_cast(h2, v3.y);
        W.w6_[2] = __builtin_bit_cast(h2, v3.z); W.w6_[3] = __builtin_bit_cast(h2, v3.w);
        W.al01   = __builtin_bit_cast(h2, v4.x); W.al23   = __builtin_bit_cast(h2, v4.y);
    }

    float ri = r[node];
    int e0 = off[node], e1 = off[node + 1];

    float4 s = make_float4(0.f, 0.f, 0.f, 0.f);
    float den = 0.f;
    if (e0 < e1) {
        int last = e1 - 1;
        // prologue: records for the first 16-edge group
        int ea = e0 + q, eb = ea + 4, ec = ea + 8, ed = ea + 12;
        uint4 ra = rec[ea < e1 ? ea : last];
        uint4 rb = rec[eb < e1 ? eb : last];
        uint4 rc = rec[ec < e1 ? ec : last];
        uint4 rd = rec[ed < e1 ? ed : last];
        for (int e = e0; e < e1; e += 16) {
            // issue current g-gathers (recs already resident from prev iter)
            uint2 ga = *(const uint2*)(g + (size_t)(ra.w >> 16) * 64 + 4 * l16);
            uint2 gb = *(const uint2*)(g + (size_t)(rb.w >> 16) * 64 + 4 * l16);
            uint2 gc = *(const uint2*)(g + (size_t)(rc.w >> 16) * 64 + 4 * l16);
            uint2 gd = *(const uint2*)(g + (size_t)(rd.w >> 16) * 64 + 4 * l16);
            // prefetch next iteration's records (clamped, always safe)
            int en = e + 16;
            int fa = en + q, fb = fa + 4, fc = fa + 8, fd = fa + 12;
            uint4 na = rec[fa < e1 ? fa : last];
            uint4 nb = rec[fb < e1 ? fb : last];
            uint4 nc = rec[fc < e1 ? fc : last];
            uint4 nd = rec[fd < e1 ? fd : last];
            bool va = (e + q)      < e1, vb = (e + 4 + q)  < e1;
            bool vc = (e + 8 + q)  < e1, vd = (e + 12 + q) < e1;
            edge_math(ra, ga, va, ri, W, s, den);
            edge_math(rb, gb, vb, ri, W, s, den);
            edge_math(rc, gc, vc, ri, W, s, den);
            edge_math(rd, gd, vd, ri, W, s, den);
            ra = na; rb = nb; rc = nc; rd = nd;
        }
    }
    s.x = x16_32_sum(s.x); s.y = x16_32_sum(s.y);
    s.z = x16_32_sum(s.z); s.w = x16_32_sum(s.w);
    den = x16_32_sum(den);
    float inv = 1.f / (den + 1e-16f);
    if (q == 0) {
        float4 o = make_float4(s.x * inv, s.y * inv, s.z * inv, s.w * inv);
        *(float4*)(aggdst + (size_t)node * 256 + 4 * l16) = o;
    }
}

// ---------------- fused final gemm2 (layer 2) + head ----------------
// h3 = relu(agg2@W2 + b) stays in LDS (never written to hcat);
// head: z = relu(hcat[:,0:192]·f1w + h3·f1w[192:] + f1b); out = sigmoid(z·f2w + f2b)
__global__ __launch_bounds__(256) void k_gemm2head(
    const float* __restrict__ hcat,
    const float* __restrict__ W2, const float* __restrict__ bias,
    const float* __restrict__ f1w, const float* __restrict__ f1b,
    const float* __restrict__ f2w, const float* __restrict__ f2b,
    float* __restrict__ out, int N)
{
    __shared__ __align__(16) float sA[64][132];   // gemm A staging, then sO[128][65]
    __shared__ __align__(16) float sBW[5120];     // W2 (4096), then f1w (5120)
    __shared__ float sP[128 * 20];                // partial z from upper half
    int tid = threadIdx.x, row0 = blockIdx.x * 128;

    {
        const float4* b4 = (const float4*)W2;
        float4* s4 = (float4*)sBW;
        for (int i = tid; i < 1024; i += 256) s4[i] = b4[i];
    }
#pragma unroll
    for (int pass = 0; pass < 8; ++pass) {
        int nl = pass * 16 + (tid & 15);
        int k4 = (tid >> 4) * 4;
        int n = row0 + nl; if (n >= N) n = N - 1;
        float4 v = *(const float4*)(hcat + (size_t)n * 256 + 192 + k4);
        sA[k4 + 0][nl] = v.x; sA[k4 + 1][nl] = v.y;
        sA[k4 + 2][nl] = v.z; sA[k4 + 3][nl] = v.w;
    }
    __syncthreads();

    int tr = tid >> 4, tc = tid & 15;
    int r0 = tr * 8, c0 = tc * 4;
    float acc[8][4];
#pragma unroll
    for (int i = 0; i < 8; i++)
#pragma unroll
        for (int j = 0; j < 4; j++) acc[i][j] = 0.f;

#pragma unroll 4
    for (int k = 0; k < 64; ++k) {
        float4 b4 = *(const float4*)(sBW + k * 64 + c0);
        float4 a0 = *(const float4*)&sA[k][r0];
        float4 a1 = *(const float4*)&sA[k][r0 + 4];
#pragma unroll
        for (int j = 0; j < 4; j++) {
            float bj = (&b4.x)[j];
            acc[0][j] += a0.x * bj; acc[1][j] += a0.y * bj;
            acc[2][j] += a0.z * bj; acc[3][j] += a0.w * bj;
            acc[4][j] += a1.x * bj; acc[5][j] += a1.y * bj;
            acc[6][j] += a1.z * bj; acc[7][j] += a1.w * bj;
        }
    }

    // issue f1w loads early (write to LDS only after the sync)
    float4 fw[5];
    {
        const float4* w4 = (const float4*)f1w;
#pragma unroll
        for (int i2 = 0; i2 < 5; i2++) fw[i2] = w4[tid + i2 * 256];
    }
    __syncthreads();   // everyone done reading sA/sBW

    float* sO = &sA[0][0];          // [128][65] = 8320 <= 8448 floats
    float4 bv = *(const float4*)(bias + c0);
#pragma unroll
    for (int i = 0; i < 8; i++) {
        acc[i][0] = fmaxf(acc[i][0] + bv.x, 0.f);
        acc[i][1] = fmaxf(acc[i][1] + bv.y, 0.f);
        acc[i][2] = fmaxf(acc[i][2] + bv.z, 0.f);
        acc[i][3] = fmaxf(acc[i][3] + bv.w, 0.f);
        int rr = r0 + i;
        sO[rr * 65 + c0 + 0] = acc[i][0];
        sO[rr * 65 + c0 + 1] = acc[i][1];
        sO[rr * 65 + c0 + 2] = acc[i][2];
        sO[rr * 65 + c0 + 3] = acc[i][3];
    }
    {
        float4* sw4 = (float4*)sBW;
#pragma unroll
        for (int i2 = 0; i2 < 5; i2++) sw4[tid + i2 * 256] = fw[i2];
    }
    __syncthreads();

    // head: 2 threads per row; half 0 -> k 0..127, half 1 -> k 128..255
    int rloc = tid & 127;
    int half = tid >> 7;
    int n = row0 + rloc;
    int nn = (n < N) ? n : N - 1;
    float z[20];
#pragma unroll
    for (int j = 0; j < 20; j++) z[j] = 0.f;
    const float4* hr = (const float4*)(hcat + (size_t)nn * 256);
    if (half == 0) {
        for (int k4 = 0; k4 < 32; k4++) {
            float4 h = hr[k4];
            const float* wr = sBW + k4 * 80;
#pragma unroll
            for (int j = 0; j < 20; j++)
                z[j] += h.x * wr[j] + h.y * wr[20 + j] + h.z * wr[40 + j] + h.w * wr[60 + j];
        }
    } else {
        for (int k4 = 32; k4 < 48; k4++) {
            float4 h = hr[k4];
            const float* wr = sBW + k4 * 80;
#pragma unroll
            for (int j = 0; j < 20; j++)
                z[j] += h.x * wr[j] + h.y * wr[20 + j] + h.z * wr[40 + j] + h.w * wr[60 + j];
        }
        for (int k = 0; k < 64; k += 2) {
            float hx = sO[rloc * 65 + k], hy = sO[rloc * 65 + k + 1];
            const float* wr = sBW + (192 + k) * 20;
#pragma unroll
            for (int j = 0; j < 20; j++)
                z[j] += hx * wr[j] + hy * wr[20 + j];
        }
#pragma unroll
        for (int j = 0; j < 20; j++) sP[rloc * 20 + j] = z[j];
    }
    __syncthreads();
    if (half == 0 && n < N) {
        float o = f2b[0];
#pragma unroll
        for (int j = 0; j < 20; j++) {
            float zj = z[j] + sP[rloc * 20 + j] + f1b[j];
            o += fmaxf(zj, 0.f) * f2w[j];
        }
        out[n] = 1.f / (1.f + __expf(-o));
    }
}

extern "C" void kernel_launch(void* const* d_in, const int* in_sizes, int n_in,
                              void* d_out, int out_size, void* d_ws, size_t ws_size,
                              hipStream_t stream) {
    const int*   x     = (const int*)d_in[0];
    const int*   eidx  = (const int*)d_in[1];
    const float* eattr = (const float*)d_in[2];
    const float* emb   = (const float*)d_in[3];
    const float* lin1  = (const float*)d_in[4];   // [3,71,64]
    const float* attl  = (const float*)d_in[5];   // [3,64]
    const float* attr_ = (const float*)d_in[6];   // [3,64]
    const float* lin2  = (const float*)d_in[7];   // [3,64,64]
    const float* gbias = (const float*)d_in[8];   // [3,64]
    const float* f1w   = (const float*)d_in[9];   // [256,20]
    const float* f1b   = (const float*)d_in[10];
    const float* f2w   = (const float*)d_in[11];
    const float* f2b   = (const float*)d_in[12];
    float* out = (float*)d_out;

    int N = in_sizes[0];
    int E = in_sizes[1] / 2;
    const int* src = eidx;
    const int* dst = eidx + E;

    // workspace carve (256B aligned)
    char* p = (char*)d_ws;
    auto alloc = [&](size_t bytes) { void* q = (void*)p; p += (bytes + 255) & ~(size_t)255; return q; };
    float* hcat = (float*)alloc((size_t)N * 256 * 4);
    f16*   g    = (f16*)alloc((size_t)N * 64 * 2);
    float* r    = (float*)alloc((size_t)N * 4);
    int*   off  = (int*)alloc((size_t)(N + 1) * 4);
    int*   deg  = (int*)alloc((size_t)N * 4);
    int*   rank = (int*)alloc((size_t)E * 4);
    int*   bsum = (int*)alloc(256 * 4);
    uint4* rec  = (uint4*)alloc((size_t)E * 16);   // 16 B/edge: fp16 attrs + u16 src
    uint4* wpack = (uint4*)alloc((size_t)48 * 5 * 16);  // packed conv weights, 3 layers

    int nbs   = (N + 1023) / 1024;     // 49 scan blocks (<=256)
    int nbE   = (E + 255) / 256;
    int nbG0  = (N + 15) / 16;         // 3125 layer-0 gemm tiles (16-row, ~21KB LDS)
    int nbg64 = (N + 63) / 64;
    int nbg128 = (N + 127) / 128;
    int nbc   = (N + 3) / 4;

    k_zero<<<(N + 255) / 256, 256, 0, stream>>>(deg, N, lin1, attl, wpack);
    // CSR count (rank) overlapped with layer-0 gemm (16-row tiles, small LDS)
    k_count_gemm<<<nbE + nbG0, 256, 0, stream>>>(dst, deg, rank, E, nbE,
                                                 x, emb, lin1, attr_, g, r, hcat, N);
    k_scan_part<<<nbs, 256, 0, stream>>>(deg, bsum, N);
    k_scan_out<<<nbs, 256, 0, stream>>>(deg, bsum, off, nbs, N);
    k_fill<<<nbE, 256, 0, stream>>>(src, dst, eattr, off, rank, rec, E);

    k_conv<<<nbc, 256, 0, stream>>>(off, rec, g, r, wpack, hcat + 64, N);
    for (int l = 0; l < 2; l++) {
        k_gemm2g1<<<nbg64, 256, 0, stream>>>(hcat + 64 * (l + 1),
                                             lin2 + (size_t)l * 4096, gbias + l * 64,
                                             lin1 + (size_t)(l + 1) * 71 * 64,
                                             attr_ + (l + 1) * 64, g, r, N);
        k_conv<<<nbc, 256, 0, stream>>>(off, rec, g, r,
                                        wpack + (size_t)(l + 1) * 80,
                                        hcat + 64 * (l + 2), N);
    }
    // fused final gemm2 (layer 2) + head: h3 never touches HBM
    k_gemm2head<<<nbg128, 256, 0, stream>>>(hcat, lin2 + 2 * 4096, gbias + 128,
                                            f1w, f1b, f2w, f2b, out, N);
}